// Round 20
// baseline (1199.644 us; speedup 1.0000x reference)
//
#include <hip/hip_runtime.h>
#include <hip/hip_bf16.h>

#define BEV 180
#define NPOS (BEV * BEV)   // 32400
#define MTOT (2 * NPOS)    // 64800
#define IH 64
#define IW 176
#define CIMG 256

typedef __attribute__((ext_vector_type(8))) short bf16x8;
typedef __attribute__((ext_vector_type(4))) short bf16x4;
typedef __attribute__((ext_vector_type(4))) float f32x4;

__device__ __forceinline__ float bf2f(short s) {
  return __uint_as_float(((unsigned)(unsigned short)s) << 16);
}
__device__ __forceinline__ short f2bf(float f) {
  union { __hip_bfloat16 h; short s; } u;
  u.h = __float2bfloat16(f);
  return u.s;
}

__device__ __forceinline__ void gload_lds16(const void* g, void* l) {
  __builtin_amdgcn_global_load_lds(
      (const __attribute__((address_space(1))) void*)g,
      (__attribute__((address_space(3))) void*)l, 16, 0, 0);
}

// ---------------- zero page ----------------
__global__ void k_zero(unsigned long long* p) { p[threadIdx.x] = 0ULL; }

// ---------------- generic fp32 [B][R][CL] -> [B][CL][R] transpose ----------------
template <typename OT>
__device__ __forceinline__ OT conv_out(float v);
template <>
__device__ __forceinline__ float conv_out<float>(float v) { return v; }
template <>
__device__ __forceinline__ __hip_bfloat16 conv_out<__hip_bfloat16>(float v) { return __float2bfloat16(v); }

template <typename OT>
__global__ void k_transpose(const float* __restrict__ in, OT* __restrict__ out, int R, int CL) {
  __shared__ float tile[32][33];
  const float* inb = in + (size_t)blockIdx.z * R * CL;
  OT* outb = out + (size_t)blockIdx.z * R * CL;
  int c0 = blockIdx.x * 32, r0 = blockIdx.y * 32;
  int tx = threadIdx.x, ty = threadIdx.y;
#pragma unroll
  for (int i = 0; i < 32; i += 8) {
    int r = r0 + ty + i, c = c0 + tx;
    tile[ty + i][tx] = (r < R && c < CL) ? inb[(size_t)r * CL + c] : 0.f;
  }
  __syncthreads();
#pragma unroll
  for (int i = 0; i < 32; i += 8) {
    int c = c0 + ty + i, r = r0 + tx;
    if (c < CL && r < R) outb[(size_t)c * R + r] = conv_out<OT>(tile[tx][ty + i]);
  }
}

// ---------------- projection + bilinear sample -> image_bev NHWC bf16 ----------------
// imgT is NHWC bf16. 4 positions per block; each 64-lane group handles one
// position with 4 channels/thread via bf16x4 (8 B/lane) corner loads.
__global__ void k_sample(const __hip_bfloat16* __restrict__ imgT, const float* __restrict__ l2i,
                         __hip_bfloat16* __restrict__ out) {
  const int t = threadIdx.x;
  const int pos = blockIdx.x * 4 + (t >> 6);
  const int b = pos / NPOS, rem = pos - b * NPOS;
  const int hy = rem / BEV, wx = rem - hy * BEV;
  const int c4 = (t & 63) * 4;
  float gx = -54.f + 0.3f + 0.6f * (float)wx;
  float gy = -54.f + 0.3f + 0.6f * (float)hy;
  const float* L = l2i + b * 12;
  const __hip_bfloat16* img = imgT + (size_t)b * (IH * IW * CIMG);
  float acc0 = 0.f, acc1 = 0.f, acc2 = 0.f, acc3 = 0.f, vcnt = 0.f;
#pragma unroll
  for (int zi = 0; zi < 3; ++zi) {
    float z = (float)(zi - 1);
    float p0 = L[0] * gx + L[1] * gy + L[2] * z + L[3];
    float p1 = L[4] * gx + L[5] * gy + L[6] * z + L[7];
    float p2 = L[8] * gx + L[9] * gy + L[10] * z + L[11];
    float d = fmaxf(p2, 1e-5f);
    float px = p0 / d, py = p1 / d;
    if (px >= 0.f && px < 704.f && py >= 0.f && py < 256.f && p2 > 1e-5f) {
      vcnt += 1.f;
      float ix = px * 0.25f - 0.5f, iy = py * 0.25f - 0.5f;
      float xf = floorf(ix), yf = floorf(iy);
      float wx1 = ix - xf, wy1 = iy - yf;
      float wx0 = 1.f - wx1, wy0 = 1.f - wy1;
      int x0 = (int)xf, y0 = (int)yf;
      int x1 = x0 + 1, y1 = y0 + 1;
      bool bx0 = (unsigned)x0 < IW, bx1 = (unsigned)x1 < IW;
      bool by0 = (unsigned)y0 < IH, by1 = (unsigned)y1 < IH;
#define CORNER(XC, YC, W)                                                        \
      {                                                                          \
        bf16x4 v = *(const bf16x4*)&img[((size_t)(YC) * IW + (XC)) * CIMG + c4]; \
        float wgt = (W);                                                         \
        short e0 = v[0], e1 = v[1], e2 = v[2], e3 = v[3];                        \
        acc0 += wgt * bf2f(e0);                                                  \
        acc1 += wgt * bf2f(e1);                                                  \
        acc2 += wgt * bf2f(e2);                                                  \
        acc3 += wgt * bf2f(e3);                                                  \
      }
      if (bx0 && by0) CORNER(x0, y0, wx0 * wy0);
      if (bx1 && by0) CORNER(x1, y0, wx1 * wy0);
      if (bx0 && by1) CORNER(x0, y1, wx0 * wy1);
      if (bx1 && by1) CORNER(x1, y1, wx1 * wy1);
#undef CORNER
    }
  }
  float inv = 1.f / fmaxf(vcnt, 1.f);
  bf16x4 o;
  o[0] = f2bf(acc0 * inv);
  o[1] = f2bf(acc1 * inv);
  o[2] = f2bf(acc2 * inv);
  o[3] = f2bf(acc3 * inv);
  *(bf16x4*)&out[(size_t)pos * CIMG + c4] = o;
}

// ---------------- weight pack: w[co][ci][tap] fp32 -> wp[tap][co][ci] bf16 ----------------
__global__ void k_packw(const float* __restrict__ w, __hip_bfloat16* __restrict__ wp,
                        int Co, int Ci, int T) {
  size_t idx = (size_t)blockIdx.x * 256 + threadIdx.x;
  size_t tot = (size_t)Co * Ci * T;
  if (idx >= tot) return;
  int ci = (int)(idx % Ci);
  size_t r = idx / Ci;
  int co = (int)(r % Co);
  int tap = (int)(r / Co);
  wp[idx] = __float2bfloat16(w[((size_t)co * Ci + ci) * T + tap]);
}

// ---------------- BN fold: [4][C] -> [2][C] (scale, bias) ----------------
__global__ void k_packbn(const float* __restrict__ bn, float* __restrict__ sb, int C) {
  int i = blockIdx.x * blockDim.x + threadIdx.x;
  if (i >= C) return;
  float g = bn[i], b = bn[C + i], m = bn[2 * C + i], v = bn[3 * C + i];
  float s = g / sqrtf(v + 1e-5f);
  sb[i] = s;
  sb[C + i] = b - m * s;
}

// ---------------- implicit-GEMM conv: 256x128 block, 128x64 wave tile ----------------
// Round-17 structure (best) with FULLY COMPILE-TIME phase bookkeeping: templated
// on (TAPS, CIN0, CIN1) so nA is constexpr; kc loop (unroll 1) x tap loop (full
// unroll) -> dy/dx, next-tap index, weight-tap offsets and sRow0 deltas all fold
// to constants, removing the per-phase integer div/mod and loop-carried VALU.
// Addresses, barriers, buffers and staging are byte-identical to round 17.
template <int TAPS, int CIN0, int CIN1>
__global__ __launch_bounds__(256, 2) void k_conv(
    const __hip_bfloat16* __restrict__ x0, const __hip_bfloat16* __restrict__ x1,
    const __hip_bfloat16* __restrict__ wp, const float* __restrict__ sb,
    int isFinal,
    __hip_bfloat16* __restrict__ obf, float* __restrict__ of32,
    const __hip_bfloat16* __restrict__ zp) {
  const int Cout = 384;
  constexpr int cinTot = CIN0 + CIN1;
  constexpr int nA0 = CIN0 >> 6, nA1 = CIN1 >> 6, nA = nA0 + nA1;
  constexpr size_t tapStride = (size_t)384 * cinTot * 2;  // bytes per tap in wp
  __shared__ __hip_bfloat16 As[352 * 64];       // 45056 B  [halo row s][64 ch]
  __shared__ __hip_bfloat16 Bs[2][128 * 64];    // 2 x 16384 B  [cout r][64 ch]
  const int t = threadIdx.x;
  const int w = t >> 6, l = t & 63;
  const int bid = blockIdx.x;
  const int b = bid / 144;
  const int rr = bid - b * 144;
  const int y0 = (rr / 12) * 16;
  const int x0c = (rr - (rr / 12) * 12) * 16;
  const int n0 = blockIdx.y * 128;

  // ---- A staging precompute: 11 issues x 256 threads -> 352 rows of 128 B ----
  const int baseRow = t >> 3;
  const int cb = ((t & 7) ^ (baseRow & 7)) * 16;   // XOR-8 pre-swizzle
  int posIdx[11];
  unsigned okMask = 0;
#pragma unroll
  for (int j = 0; j < 11; ++j) {
    int row = j * 32 + baseRow;
    int yy = row / 18, xx = row - yy * 18;
    int ys = y0 - 1 + yy, xg = x0c - 1 + xx;
    if (row < 324 && (unsigned)ys < 180u && (unsigned)xg < 180u) okMask |= (1u << j);
    posIdx[j] = b * NPOS + ys * BEV + xg;
  }
  // ---- B staging precompute (4 issues) ----
  size_t bOff[4];
#pragma unroll
  for (int j = 0; j < 4; ++j)
    bOff[j] = (size_t)(n0 + j * 32 + baseRow) * (size_t)(cinTot * 2) + (size_t)cb;

  auto issueA = [&](int kc) {  // stage A chunk kc into the single A buffer
    const bool s1 = (kc >= nA0);
    int kcw = kc - (s1 ? nA0 : 0);
    const char* xb = s1 ? (const char*)x1 : (const char*)x0;
    size_t cinB = (size_t)(s1 ? CIN1 : CIN0) * 2;
    size_t ko = (size_t)kcw * 128 + (size_t)cb;
    char* dst = (char*)As + w * 1024;
#pragma unroll
    for (int j = 0; j < 11; ++j) {
      const char* src = ((okMask >> j) & 1) ? (xb + (size_t)posIdx[j] * cinB + ko)
                                            : (const char*)zp;
      gload_lds16(src, dst + j * 4096);
    }
  };
  auto issueB = [&](int q, int kc, int tq) {  // stage B (tap tq of chunk kc) -> Bs[q&1]
    const bool s1 = (kc >= nA0);
    int kcw = kc - (s1 ? nA0 : 0);
    int segoff = s1 ? CIN0 : 0;
    const char* wt = (const char*)wp + (size_t)tq * tapStride + (size_t)(segoff + kcw * 64) * 2;
    char* dst = (char*)Bs[q & 1] + w * 1024;
#pragma unroll
    for (int j = 0; j < 4; ++j) gload_lds16(wt + bOff[j], dst + j * 4096);
  };

  f32x4 acc[8][4];
#pragma unroll
  for (int mi = 0; mi < 8; ++mi)
#pragma unroll
    for (int ni = 0; ni < 4; ++ni) acc[mi][ni] = f32x4{0.f, 0.f, 0.f, 0.f};

  const int wq = w >> 1;            // M half: y-rows [wq*8, wq*8+8)
  const int wn = (w & 1) * 64;      // N half base
  const int xl = l & 15, kq = l >> 4;
  const int aBase = (wq * 8 + 1) * 18 + xl + 1;   // sRow0 for dy=dx=0

  // ---- prologue ----
  issueA(0);
  issueB(0, 0, 0);

  int bufSel = 0;
#pragma unroll 1
  for (int kc = 0; kc < nA; ++kc) {
#pragma unroll
    for (int tap = 0; tap < TAPS; ++tap) {
      const int dy = (TAPS == 9) ? (tap / 3 - 1) : 0;        // compile-time
      const int dx = (TAPS == 9) ? (tap - (tap / 3) * 3 - 1) : 0;
      // top of phase: everything needed this phase is the oldest in flight
      asm volatile("s_waitcnt vmcnt(0)" ::: "memory");
      __builtin_amdgcn_s_barrier();   // B(phase)/A(kc) visible; prev reads done
      asm volatile("" ::: "memory");
      const bool lastPhase = (tap == TAPS - 1) && (kc == nA - 1);
      if (!lastPhase) {               // Bs[bufSel^1]'s last readers are behind the barrier
        const int tq = (tap + 1 == TAPS) ? 0 : tap + 1;      // compile-time
        const int kn = (tap + 1 == TAPS) ? kc + 1 : kc;
        issueB(bufSel ^ 1, kn, tq);
      }

      const int sRow0 = aBase + dy * 18 + dx;                // base + const
      const char* bLds = (const char*)Bs[bufSel];
      __builtin_amdgcn_s_setprio(1);
#pragma unroll
      for (int ks = 0; ks < 2; ++ks) {
        const int g = ks * 4 + kq;
        bf16x8 af[8], bfr[4];
#pragma unroll
        for (int mi = 0; mi < 8; ++mi) {
          int s = sRow0 + mi * 18;
          af[mi] = *(const bf16x8*)((const char*)As + s * 128 + ((g ^ (s & 7)) * 16));
        }
#pragma unroll
        for (int ni = 0; ni < 4; ++ni) {
          int rB = wn + ni * 16 + xl;
          bfr[ni] = *(const bf16x8*)(bLds + rB * 128 + ((g ^ (rB & 7)) * 16));
        }
#pragma unroll
        for (int mi = 0; mi < 8; ++mi)
#pragma unroll
          for (int ni = 0; ni < 4; ++ni)
            acc[mi][ni] = __builtin_amdgcn_mfma_f32_16x16x32_bf16(af[mi], bfr[ni], acc[mi][ni], 0, 0, 0);
      }
      __builtin_amdgcn_s_setprio(0);
      asm volatile("" ::: "memory");

      // kc boundary: WAR-protect As before re-staging
      if (tap == TAPS - 1 && kc + 1 < nA) {
        __builtin_amdgcn_s_barrier(); // all waves' A(kc) reads done
        issueA(kc + 1);
      }
      bufSel ^= 1;
    }
  }

  // ---- epilogue: BN + ReLU, store ----
  float sc[4], bi[4];
#pragma unroll
  for (int ni = 0; ni < 4; ++ni) {
    int cc = n0 + wn + ni * 16 + xl;
    sc[ni] = sb[cc];
    bi[ni] = sb[Cout + cc];
  }
#pragma unroll
  for (int mi = 0; mi < 8; ++mi) {
    int y = y0 + wq * 8 + mi;
    if (y >= BEV) continue;
#pragma unroll
    for (int j = 0; j < 4; ++j) {
      int x = x0c + kq * 4 + j;  // C/D layout: row = (lane>>4)*4 + j
      if (x >= BEV) continue;
      int pp = b * NPOS + y * BEV + x;
#pragma unroll
      for (int ni = 0; ni < 4; ++ni) {
        int cc = n0 + wn + ni * 16 + xl;
        float v = fmaxf(acc[mi][ni][j] * sc[ni] + bi[ni], 0.f);
        if (isFinal) {
          of32[((size_t)(b * Cout + cc)) * NPOS + (size_t)y * BEV + x] = v;
        } else {
          obf[(size_t)pp * Cout + cc] = __float2bfloat16(v);
        }
      }
    }
  }
}

extern "C" void kernel_launch(void* const* d_in, const int* in_sizes, int n_in,
                              void* d_out, int out_size, void* d_ws, size_t ws_size,
                              hipStream_t stream) {
  const float* radar = (const float*)d_in[0];
  const float* imgf = (const float*)d_in[1];
  const float* l2i = (const float*)d_in[2];
  const float* w1 = (const float*)d_in[3];
  const float* bn1 = (const float*)d_in[4];
  const float* w2 = (const float*)d_in[5];
  const float* bn2 = (const float*)d_in[6];
  const float* wf1 = (const float*)d_in[7];
  const float* bnf1 = (const float*)d_in[8];
  const float* wf2 = (const float*)d_in[9];
  const float* bnf2 = (const float*)d_in[10];

  char* ws = (char*)d_ws;
  size_t off = 0;
  auto alloc = [&](size_t bytes) {
    char* p = ws + off;
    off += (bytes + 255) & ~(size_t)255;
    return p;
  };
  char* zp = alloc(4096);
  char* imgT = alloc((size_t)2 * IH * IW * CIMG * 4);   // alloc kept fp32-sized; bf16 uses half
  char* ibev = alloc((size_t)MTOT * CIMG * 2);          // 33.2 MB bf16 NHWC
  char* radarT = imgT;                                  // alias spans imgT+ibev (both dead then)
  char* h1 = alloc((size_t)MTOT * 384 * 2);             // 49.8 MB
  char* h2 = alloc((size_t)MTOT * 384 * 2);             // 49.8 MB
  char* f1 = h1;                                        // alias: h1 dead after conv2
  char* wp1 = alloc((size_t)1 * 384 * 256 * 2);
  char* wp2 = alloc((size_t)9 * 384 * 384 * 2);
  char* wpf1 = alloc((size_t)9 * 384 * 768 * 2);
  char* wpf2 = alloc((size_t)9 * 384 * 384 * 2);
  char* sb1 = alloc(2 * 384 * 4);
  char* sb2 = alloc(2 * 384 * 4);
  char* sbf1 = alloc(2 * 384 * 4);
  char* sbf2 = alloc(2 * 384 * 4);

  k_zero<<<1, 512, 0, stream>>>((unsigned long long*)zp);

  dim3 tb(32, 8);
  // img_feat NCHW -> NHWC bf16 (halves sampler read traffic; interp stays fp32)
  k_transpose<__hip_bfloat16><<<dim3((IH * IW + 31) / 32, (CIMG + 31) / 32, 2), tb, 0, stream>>>(
      imgf, (__hip_bfloat16*)imgT, CIMG, IH * IW);

  auto packw = [&](const float* src, char* dst, int Co, int Ci, int T) {
    size_t tot = (size_t)Co * Ci * T;
    k_packw<<<(unsigned)((tot + 255) / 256), 256, 0, stream>>>(src, (__hip_bfloat16*)dst, Co, Ci, T);
  };
  packw(w1, wp1, 384, 256, 1);
  packw(w2, wp2, 384, 384, 9);
  packw(wf1, wpf1, 384, 768, 9);
  packw(wf2, wpf2, 384, 384, 9);
  k_packbn<<<2, 256, 0, stream>>>(bn1, (float*)sb1, 384);
  k_packbn<<<2, 256, 0, stream>>>(bn2, (float*)sb2, 384);
  k_packbn<<<2, 256, 0, stream>>>(bnf1, (float*)sbf1, 384);
  k_packbn<<<2, 256, 0, stream>>>(bnf2, (float*)sbf2, 384);

  // sampling -> image_bev NHWC bf16 (4 pos/block, bf16x4 per-lane loads)
  k_sample<<<MTOT / 4, 256, 0, stream>>>((const __hip_bfloat16*)imgT, l2i, (__hip_bfloat16*)ibev);

  dim3 cg(288, 3);   // 288 M-tiles (12x12 spatial x 2 batch) x 3 N-blocks
  // conv1: 1x1, image_bev(256) -> h1(384)
  k_conv<1, 256, 0><<<cg, 256, 0, stream>>>((const __hip_bfloat16*)ibev, nullptr,
                                            (const __hip_bfloat16*)wp1, (const float*)sb1, 0,
                                            (__hip_bfloat16*)h1, nullptr, (const __hip_bfloat16*)zp);
  // radar NCHW -> NHWC bf16 (aliases imgT/ibev — both dead after conv1)
  k_transpose<__hip_bfloat16><<<dim3((NPOS + 31) / 32, (384 + 31) / 32, 2), tb, 0, stream>>>(
      radar, (__hip_bfloat16*)radarT, 384, NPOS);
  // conv2: 3x3, h1(384) -> h2(384)
  k_conv<9, 384, 0><<<cg, 256, 0, stream>>>((const __hip_bfloat16*)h1, nullptr,
                                            (const __hip_bfloat16*)wp2, (const float*)sb2, 0,
                                            (__hip_bfloat16*)h2, nullptr, (const __hip_bfloat16*)zp);
  // convf1: 3x3, concat(radar, h2)(768) -> f1(384)
  k_conv<9, 384, 384><<<cg, 256, 0, stream>>>((const __hip_bfloat16*)radarT, (const __hip_bfloat16*)h2,
                                              (const __hip_bfloat16*)wpf1, (const float*)sbf1, 0,
                                              (__hip_bfloat16*)f1, nullptr, (const __hip_bfloat16*)zp);
  // convf2: 3x3, f1(384) -> d_out fp32 NCHW
  k_conv<9, 384, 0><<<cg, 256, 0, stream>>>((const __hip_bfloat16*)f1, nullptr,
                                            (const __hip_bfloat16*)wpf2, (const float*)sbf2, 1,
                                            nullptr, (float*)d_out, (const __hip_bfloat16*)zp);
}

// Round 21
// 906.769 us; speedup vs baseline: 1.3230x; 1.3230x over previous
//
#include <hip/hip_runtime.h>
#include <hip/hip_bf16.h>

#define BEV 180
#define NPOS (BEV * BEV)   // 32400
#define MTOT (2 * NPOS)    // 64800
#define IH 64
#define IW 176
#define CIMG 256

typedef __attribute__((ext_vector_type(8))) short bf16x8;
typedef __attribute__((ext_vector_type(4))) short bf16x4;
typedef __attribute__((ext_vector_type(4))) float f32x4;

__device__ __forceinline__ float bf2f(short s) {
  return __uint_as_float(((unsigned)(unsigned short)s) << 16);
}
__device__ __forceinline__ short f2bf(float f) {
  union { __hip_bfloat16 h; short s; } u;
  u.h = __float2bfloat16(f);
  return u.s;
}

__device__ __forceinline__ void gload_lds16(const void* g, void* l) {
  __builtin_amdgcn_global_load_lds(
      (const __attribute__((address_space(1))) void*)g,
      (__attribute__((address_space(3))) void*)l, 16, 0, 0);
}

// ---------------- zero page ----------------
__global__ void k_zero(unsigned long long* p) { p[threadIdx.x] = 0ULL; }

// ---------------- generic fp32 [B][R][CL] -> [B][CL][R] transpose ----------------
template <typename OT>
__device__ __forceinline__ OT conv_out(float v);
template <>
__device__ __forceinline__ float conv_out<float>(float v) { return v; }
template <>
__device__ __forceinline__ __hip_bfloat16 conv_out<__hip_bfloat16>(float v) { return __float2bfloat16(v); }

template <typename OT>
__global__ void k_transpose(const float* __restrict__ in, OT* __restrict__ out, int R, int CL) {
  __shared__ float tile[32][33];
  const float* inb = in + (size_t)blockIdx.z * R * CL;
  OT* outb = out + (size_t)blockIdx.z * R * CL;
  int c0 = blockIdx.x * 32, r0 = blockIdx.y * 32;
  int tx = threadIdx.x, ty = threadIdx.y;
#pragma unroll
  for (int i = 0; i < 32; i += 8) {
    int r = r0 + ty + i, c = c0 + tx;
    tile[ty + i][tx] = (r < R && c < CL) ? inb[(size_t)r * CL + c] : 0.f;
  }
  __syncthreads();
#pragma unroll
  for (int i = 0; i < 32; i += 8) {
    int c = c0 + ty + i, r = r0 + tx;
    if (c < CL && r < R) outb[(size_t)c * R + r] = conv_out<OT>(tile[tx][ty + i]);
  }
}

// ---------------- projection + bilinear sample -> image_bev NHWC bf16 ----------------
// imgT is NHWC bf16. 4 positions per block; each 64-lane group handles one
// position with 4 channels/thread via bf16x4 (8 B/lane) corner loads.
__global__ void k_sample(const __hip_bfloat16* __restrict__ imgT, const float* __restrict__ l2i,
                         __hip_bfloat16* __restrict__ out) {
  const int t = threadIdx.x;
  const int pos = blockIdx.x * 4 + (t >> 6);
  const int b = pos / NPOS, rem = pos - b * NPOS;
  const int hy = rem / BEV, wx = rem - hy * BEV;
  const int c4 = (t & 63) * 4;
  float gx = -54.f + 0.3f + 0.6f * (float)wx;
  float gy = -54.f + 0.3f + 0.6f * (float)hy;
  const float* L = l2i + b * 12;
  const __hip_bfloat16* img = imgT + (size_t)b * (IH * IW * CIMG);
  float acc0 = 0.f, acc1 = 0.f, acc2 = 0.f, acc3 = 0.f, vcnt = 0.f;
#pragma unroll
  for (int zi = 0; zi < 3; ++zi) {
    float z = (float)(zi - 1);
    float p0 = L[0] * gx + L[1] * gy + L[2] * z + L[3];
    float p1 = L[4] * gx + L[5] * gy + L[6] * z + L[7];
    float p2 = L[8] * gx + L[9] * gy + L[10] * z + L[11];
    float d = fmaxf(p2, 1e-5f);
    float px = p0 / d, py = p1 / d;
    if (px >= 0.f && px < 704.f && py >= 0.f && py < 256.f && p2 > 1e-5f) {
      vcnt += 1.f;
      float ix = px * 0.25f - 0.5f, iy = py * 0.25f - 0.5f;
      float xf = floorf(ix), yf = floorf(iy);
      float wx1 = ix - xf, wy1 = iy - yf;
      float wx0 = 1.f - wx1, wy0 = 1.f - wy1;
      int x0 = (int)xf, y0 = (int)yf;
      int x1 = x0 + 1, y1 = y0 + 1;
      bool bx0 = (unsigned)x0 < IW, bx1 = (unsigned)x1 < IW;
      bool by0 = (unsigned)y0 < IH, by1 = (unsigned)y1 < IH;
#define CORNER(XC, YC, W)                                                        \
      {                                                                          \
        bf16x4 v = *(const bf16x4*)&img[((size_t)(YC) * IW + (XC)) * CIMG + c4]; \
        float wgt = (W);                                                         \
        short e0 = v[0], e1 = v[1], e2 = v[2], e3 = v[3];                        \
        acc0 += wgt * bf2f(e0);                                                  \
        acc1 += wgt * bf2f(e1);                                                  \
        acc2 += wgt * bf2f(e2);                                                  \
        acc3 += wgt * bf2f(e3);                                                  \
      }
      if (bx0 && by0) CORNER(x0, y0, wx0 * wy0);
      if (bx1 && by0) CORNER(x1, y0, wx1 * wy0);
      if (bx0 && by1) CORNER(x0, y1, wx0 * wy1);
      if (bx1 && by1) CORNER(x1, y1, wx1 * wy1);
#undef CORNER
    }
  }
  float inv = 1.f / fmaxf(vcnt, 1.f);
  bf16x4 o;
  o[0] = f2bf(acc0 * inv);
  o[1] = f2bf(acc1 * inv);
  o[2] = f2bf(acc2 * inv);
  o[3] = f2bf(acc3 * inv);
  *(bf16x4*)&out[(size_t)pos * CIMG + c4] = o;
}

// ---------------- weight pack: w[co][ci][tap] fp32 -> wp[tap][co][ci] bf16 ----------------
__global__ void k_packw(const float* __restrict__ w, __hip_bfloat16* __restrict__ wp,
                        int Co, int Ci, int T) {
  size_t idx = (size_t)blockIdx.x * 256 + threadIdx.x;
  size_t tot = (size_t)Co * Ci * T;
  if (idx >= tot) return;
  int ci = (int)(idx % Ci);
  size_t r = idx / Ci;
  int co = (int)(r % Co);
  int tap = (int)(r / Co);
  wp[idx] = __float2bfloat16(w[((size_t)co * Ci + ci) * T + tap]);
}

// ---------------- BN fold: [4][C] -> [2][C] (scale, bias) ----------------
__global__ void k_packbn(const float* __restrict__ bn, float* __restrict__ sb, int C) {
  int i = blockIdx.x * blockDim.x + threadIdx.x;
  if (i >= C) return;
  float g = bn[i], b = bn[C + i], m = bn[2 * C + i], v = bn[3 * C + i];
  float s = g / sqrtf(v + 1e-5f);
  sb[i] = s;
  sb[C + i] = b - m * s;
}

// ---------------- implicit-GEMM conv: 256x128 block, 128x64 wave tile ----------------
// Round-17 structure (best, 912 us): 16x16 spatial tile, 11-issue halo stage,
// XOR-8 swizzle, B dbuf issued after the top barrier, one barrier per tap +
// one per kc boundary, counted waits, setprio'd MFMA cluster, 2 blocks/CU.
template <int TAPS>
__global__ __launch_bounds__(256, 2) void k_conv(
    const __hip_bfloat16* __restrict__ x0, const __hip_bfloat16* __restrict__ x1,
    int cin0, int cin1,
    const __hip_bfloat16* __restrict__ wp, const float* __restrict__ sb,
    int isFinal,
    __hip_bfloat16* __restrict__ obf, float* __restrict__ of32,
    const __hip_bfloat16* __restrict__ zp) {
  const int Cout = 384;
  __shared__ __hip_bfloat16 As[352 * 64];       // 45056 B  [halo row s][64 ch]
  __shared__ __hip_bfloat16 Bs[2][128 * 64];    // 2 x 16384 B  [cout r][64 ch]
  const int t = threadIdx.x;
  const int w = t >> 6, l = t & 63;
  const int bid = blockIdx.x;
  const int b = bid / 144;
  const int rr = bid - b * 144;
  const int y0 = (rr / 12) * 16;
  const int x0c = (rr - (rr / 12) * 12) * 16;
  const int n0 = blockIdx.y * 128;
  const int cinTot = cin0 + cin1;
  const size_t tapStride = (size_t)Cout * cinTot * 2;  // bytes per tap in wp
  const int nA0 = cin0 >> 6, nA1 = cin1 >> 6, nA = nA0 + nA1;
  const int P = nA * TAPS;

  // ---- A staging precompute: 11 issues x 256 threads -> 352 rows of 128 B ----
  const int baseRow = t >> 3;
  const int cb = ((t & 7) ^ (baseRow & 7)) * 16;   // XOR-8 pre-swizzle
  int posIdx[11];
  unsigned okMask = 0;
#pragma unroll
  for (int j = 0; j < 11; ++j) {
    int row = j * 32 + baseRow;
    int yy = row / 18, xx = row - yy * 18;
    int ys = y0 - 1 + yy, xg = x0c - 1 + xx;
    if (row < 324 && (unsigned)ys < 180u && (unsigned)xg < 180u) okMask |= (1u << j);
    posIdx[j] = b * NPOS + ys * BEV + xg;
  }
  // ---- B staging precompute (4 issues) ----
  size_t bOff[4];
#pragma unroll
  for (int j = 0; j < 4; ++j)
    bOff[j] = (size_t)(n0 + j * 32 + baseRow) * (size_t)(cinTot * 2) + (size_t)cb;

  auto issueA = [&](int kc) {  // stage A chunk kc into the single A buffer
    int s1 = (kc >= nA0);
    int kcw = kc - (s1 ? nA0 : 0);
    const char* xb = s1 ? (const char*)x1 : (const char*)x0;
    size_t cinB = (size_t)(s1 ? cin1 : cin0) * 2;
    size_t ko = (size_t)kcw * 128 + (size_t)cb;
    char* dst = (char*)As + w * 1024;
#pragma unroll
    for (int j = 0; j < 11; ++j) {
      const char* src = ((okMask >> j) & 1) ? (xb + (size_t)posIdx[j] * cinB + ko)
                                            : (const char*)zp;
      gload_lds16(src, dst + j * 4096);
    }
  };
  auto issueB = [&](int q, int kc, int tq) {  // stage B for phase q -> Bs[q&1]
    int s1 = (kc >= nA0);
    int kcw = kc - (s1 ? nA0 : 0);
    int segoff = s1 ? cin0 : 0;
    const char* wt = (const char*)wp + (size_t)tq * tapStride + (size_t)(segoff + kcw * 64) * 2;
    char* dst = (char*)Bs[q & 1] + w * 1024;
#pragma unroll
    for (int j = 0; j < 4; ++j) gload_lds16(wt + bOff[j], dst + j * 4096);
  };

  f32x4 acc[8][4];
#pragma unroll
  for (int mi = 0; mi < 8; ++mi)
#pragma unroll
    for (int ni = 0; ni < 4; ++ni) acc[mi][ni] = f32x4{0.f, 0.f, 0.f, 0.f};

  const int wq = w >> 1;            // M half: y-rows [wq*8, wq*8+8)
  const int wn = (w & 1) * 64;      // N half base
  const int xl = l & 15, kq = l >> 4;

  // ---- prologue ----
  issueA(0);
  issueB(0, 0, 0);

  int kc = 0, tap = 0;
  for (int p = 0; p < P; ++p) {
    // top of phase: everything needed this phase is the oldest in flight
    asm volatile("s_waitcnt vmcnt(0)" ::: "memory");
    __builtin_amdgcn_s_barrier();     // B(p)/A(kc) visible; phase p-1 reads done
    asm volatile("" ::: "memory");
    if (p + 1 < P) {                  // safe: Bs[(p+1)&1]'s last readers are behind the barrier
      int tq = tap + 1, kn = kc;
      if (tq == TAPS) { tq = 0; ++kn; }
      issueB(p + 1, kn, tq);
    }

    const int dy = (TAPS == 9) ? (tap / 3 - 1) : 0;
    const int dx = (TAPS == 9) ? (tap - (tap / 3) * 3 - 1) : 0;
    const int sRow0 = (wq * 8 + dy + 1) * 18 + xl + dx + 1;
    const char* bLds = (const char*)Bs[p & 1];
    __builtin_amdgcn_s_setprio(1);
#pragma unroll
    for (int ks = 0; ks < 2; ++ks) {
      const int g = ks * 4 + kq;
      bf16x8 af[8], bfr[4];
#pragma unroll
      for (int mi = 0; mi < 8; ++mi) {
        int s = sRow0 + mi * 18;
        af[mi] = *(const bf16x8*)((const char*)As + s * 128 + ((g ^ (s & 7)) * 16));
      }
#pragma unroll
      for (int ni = 0; ni < 4; ++ni) {
        int rB = wn + ni * 16 + xl;
        bfr[ni] = *(const bf16x8*)(bLds + rB * 128 + ((g ^ (rB & 7)) * 16));
      }
#pragma unroll
      for (int mi = 0; mi < 8; ++mi)
#pragma unroll
        for (int ni = 0; ni < 4; ++ni)
          acc[mi][ni] = __builtin_amdgcn_mfma_f32_16x16x32_bf16(af[mi], bfr[ni], acc[mi][ni], 0, 0, 0);
    }
    __builtin_amdgcn_s_setprio(0);
    asm volatile("" ::: "memory");

    // only sync point besides the top barrier: kc boundary, WAR-protect As
    if (tap == TAPS - 1 && kc + 1 < nA) {
      __builtin_amdgcn_s_barrier();   // all waves' A(kc) reads done
      issueA(kc + 1);
    }
    if (++tap == TAPS) { tap = 0; ++kc; }
  }

  // ---- epilogue: BN + ReLU, store ----
  float sc[4], bi[4];
#pragma unroll
  for (int ni = 0; ni < 4; ++ni) {
    int cc = n0 + wn + ni * 16 + xl;
    sc[ni] = sb[cc];
    bi[ni] = sb[Cout + cc];
  }
#pragma unroll
  for (int mi = 0; mi < 8; ++mi) {
    int y = y0 + wq * 8 + mi;
    if (y >= BEV) continue;
#pragma unroll
    for (int j = 0; j < 4; ++j) {
      int x = x0c + kq * 4 + j;  // C/D layout: row = (lane>>4)*4 + j
      if (x >= BEV) continue;
      int pp = b * NPOS + y * BEV + x;
#pragma unroll
      for (int ni = 0; ni < 4; ++ni) {
        int cc = n0 + wn + ni * 16 + xl;
        float v = fmaxf(acc[mi][ni][j] * sc[ni] + bi[ni], 0.f);
        if (isFinal) {
          of32[((size_t)(b * Cout + cc)) * NPOS + (size_t)y * BEV + x] = v;
        } else {
          obf[(size_t)pp * Cout + cc] = __float2bfloat16(v);
        }
      }
    }
  }
}

extern "C" void kernel_launch(void* const* d_in, const int* in_sizes, int n_in,
                              void* d_out, int out_size, void* d_ws, size_t ws_size,
                              hipStream_t stream) {
  const float* radar = (const float*)d_in[0];
  const float* imgf = (const float*)d_in[1];
  const float* l2i = (const float*)d_in[2];
  const float* w1 = (const float*)d_in[3];
  const float* bn1 = (const float*)d_in[4];
  const float* w2 = (const float*)d_in[5];
  const float* bn2 = (const float*)d_in[6];
  const float* wf1 = (const float*)d_in[7];
  const float* bnf1 = (const float*)d_in[8];
  const float* wf2 = (const float*)d_in[9];
  const float* bnf2 = (const float*)d_in[10];

  char* ws = (char*)d_ws;
  size_t off = 0;
  auto alloc = [&](size_t bytes) {
    char* p = ws + off;
    off += (bytes + 255) & ~(size_t)255;
    return p;
  };
  char* zp = alloc(4096);
  char* imgT = alloc((size_t)2 * IH * IW * CIMG * 4);   // alloc kept fp32-sized; bf16 uses half
  char* ibev = alloc((size_t)MTOT * CIMG * 2);          // 33.2 MB bf16 NHWC
  char* radarT = imgT;                                  // alias spans imgT+ibev (both dead then)
  char* h1 = alloc((size_t)MTOT * 384 * 2);             // 49.8 MB
  char* h2 = alloc((size_t)MTOT * 384 * 2);             // 49.8 MB
  char* f1 = h1;                                        // alias: h1 dead after conv2
  char* wp1 = alloc((size_t)1 * 384 * 256 * 2);
  char* wp2 = alloc((size_t)9 * 384 * 384 * 2);
  char* wpf1 = alloc((size_t)9 * 384 * 768 * 2);
  char* wpf2 = alloc((size_t)9 * 384 * 384 * 2);
  char* sb1 = alloc(2 * 384 * 4);
  char* sb2 = alloc(2 * 384 * 4);
  char* sbf1 = alloc(2 * 384 * 4);
  char* sbf2 = alloc(2 * 384 * 4);

  k_zero<<<1, 512, 0, stream>>>((unsigned long long*)zp);

  dim3 tb(32, 8);
  // img_feat NCHW -> NHWC bf16 (halves sampler read traffic; interp stays fp32)
  k_transpose<__hip_bfloat16><<<dim3((IH * IW + 31) / 32, (CIMG + 31) / 32, 2), tb, 0, stream>>>(
      imgf, (__hip_bfloat16*)imgT, CIMG, IH * IW);

  auto packw = [&](const float* src, char* dst, int Co, int Ci, int T) {
    size_t tot = (size_t)Co * Ci * T;
    k_packw<<<(unsigned)((tot + 255) / 256), 256, 0, stream>>>(src, (__hip_bfloat16*)dst, Co, Ci, T);
  };
  packw(w1, wp1, 384, 256, 1);
  packw(w2, wp2, 384, 384, 9);
  packw(wf1, wpf1, 384, 768, 9);
  packw(wf2, wpf2, 384, 384, 9);
  k_packbn<<<2, 256, 0, stream>>>(bn1, (float*)sb1, 384);
  k_packbn<<<2, 256, 0, stream>>>(bn2, (float*)sb2, 384);
  k_packbn<<<2, 256, 0, stream>>>(bnf1, (float*)sbf1, 384);
  k_packbn<<<2, 256, 0, stream>>>(bnf2, (float*)sbf2, 384);

  // sampling -> image_bev NHWC bf16 (4 pos/block, bf16x4 per-lane loads)
  k_sample<<<MTOT / 4, 256, 0, stream>>>((const __hip_bfloat16*)imgT, l2i, (__hip_bfloat16*)ibev);

  dim3 cg(288, 3);   // 288 M-tiles (12x12 spatial x 2 batch) x 3 N-blocks
  // conv1: 1x1, image_bev(256) -> h1(384)
  k_conv<1><<<cg, 256, 0, stream>>>((const __hip_bfloat16*)ibev, nullptr, 256, 0,
                                    (const __hip_bfloat16*)wp1, (const float*)sb1, 0,
                                    (__hip_bfloat16*)h1, nullptr, (const __hip_bfloat16*)zp);
  // radar NCHW -> NHWC bf16 (aliases imgT/ibev — both dead after conv1)
  k_transpose<__hip_bfloat16><<<dim3((NPOS + 31) / 32, (384 + 31) / 32, 2), tb, 0, stream>>>(
      radar, (__hip_bfloat16*)radarT, 384, NPOS);
  // conv2: 3x3, h1(384) -> h2(384)
  k_conv<9><<<cg, 256, 0, stream>>>((const __hip_bfloat16*)h1, nullptr, 384, 0,
                                    (const __hip_bfloat16*)wp2, (const float*)sb2, 0,
                                    (__hip_bfloat16*)h2, nullptr, (const __hip_bfloat16*)zp);
  // convf1: 3x3, concat(radar, h2)(768) -> f1(384)
  k_conv<9><<<cg, 256, 0, stream>>>((const __hip_bfloat16*)radarT, (const __hip_bfloat16*)h2, 384, 384,
                                    (const __hip_bfloat16*)wpf1, (const float*)sbf1, 0,
                                    (__hip_bfloat16*)f1, nullptr, (const __hip_bfloat16*)zp);
  // convf2: 3x3, f1(384) -> d_out fp32 NCHW
  k_conv<9><<<cg, 256, 0, stream>>>((const __hip_bfloat16*)f1, nullptr, 384, 0,
                                    (const __hip_bfloat16*)wpf2, (const float*)sbf2, 1,
                                    nullptr, (float*)d_out, (const __hip_bfloat16*)zp);
}